// Round 4
// baseline (60.853 us; speedup 1.0000x reference)
//
#include <hip/hip_runtime.h>
#include <cstdint>
#include <cstddef>

// SequentiallyDependentGater on MI355X — R4: pipelined streaming.
//
//   K1 proj_map : block = one 64-step chunk (64 rows of x), 4 waves x 16 rows.
//                 Per wave: noise u and th = log(u/(1-u)) for its 16 rows are
//                 resolved ONCE up front (lanes 0-15, one load + one logf),
//                 delivered per-row via __shfl -> no per-row serial load.
//                 x rows stream through a depth-2 prefetch pipeline (two
//                 4xfloat4 buffers, static rotation) so HBM latency hides
//                 under compute. Butterfly-reduced fw -> global fwu + LDS.
//                 Wave 0 then simulates all 16 start windows for the chunk
//                 (decision bitstrings traj + 16-entry end-state map).
//   K2 scan_emit: block = 4 chunks. fwu fragment + all 16 candidate trajs
//                 loaded BEFORE the scan barrier; wave 0 Hillis-Steele-scans
//                 the batch's 128 chunk maps -> starts; traj selected via
//                 __shfl. Fully parallel emit, coalesced outputs.
//
// Decision rule everywhere: samp = (logit > th), th = log(u/(1-u)) — monotone-
// equivalent to u < sigmoid(logit) incl. ties. K1's sim is the single point
// where decisions are made; K2 recomputes logit from identical fwu bits with
// the identical pure-add/select expression (bit-exact, no FMA contraction).

namespace {

constexpr int kB = 8;
constexpr int kS = 8192;
constexpr int kD = 1024;
constexpr int kRows = kB * kS;             // 65536
constexpr int kT = 64;                     // chunk length (steps)
constexpr int kCPB = kS / kT;              // 128 chunks per batch
constexpr int kChunks = kB * kCPB;         // 1024
constexpr unsigned long long kIdMap = 0xFEDCBA9876543210ull;

// window bit i = window[i] (oldest first). logit = fw0 + sum(bit_i * fw[i+1]).
// fwu row layout: [fw0, fw1, fw2, fw3] [fw4, u, th, pad]
__device__ __forceinline__ float logit_from_state(unsigned int w,
                                                  const float4& A,
                                                  const float4& Bv) {
  const float s1 = (w & 1u) ? A.y : 0.0f;
  const float s2 = (w & 2u) ? A.z : 0.0f;
  const float s3 = (w & 4u) ? A.w : 0.0f;
  const float s4 = (w & 8u) ? Bv.x : 0.0f;
  return A.x + (((s1 + s2) + s3) + s4);
}

// 16-entry 4-bit maps packed in u64; result[s] = b[a[s]] ("a then b").
__device__ __forceinline__ unsigned long long compose(unsigned long long a,
                                                      unsigned long long b) {
  unsigned long long r = 0;
#pragma unroll
  for (int s = 0; s < 16; ++s) {
    const unsigned int e = (unsigned int)(a >> (4 * s)) & 15u;
    r |= ((b >> (4 * e)) & 15ull) << (4 * s);
  }
  return r;
}

}  // namespace

// ---------------------------------------------------------------- K1
__global__ __launch_bounds__(256, 2) void proj_map_kernel(
    const float* __restrict__ x, const float* __restrict__ W,
    const float* __restrict__ noise, float* __restrict__ fwu,
    unsigned long long* __restrict__ trajbuf,
    unsigned long long* __restrict__ maps) {
  __shared__ float Wl[kD * 5];    // 20 KB
  __shared__ float fl[kT * 8];    // 2 KB chunk-local fwu
  const int tid = threadIdx.x;

  // Stage W coalesced into LDS, then into per-lane registers.
  const float4* W4 = reinterpret_cast<const float4*>(W);
  float4* Wl4 = reinterpret_cast<float4*>(Wl);
#pragma unroll
  for (int i = 0; i < 5; ++i) Wl4[tid + 256 * i] = W4[tid + 256 * i];
  __syncthreads();

  const int lane = tid & 63;
  const int wv = tid >> 6;                 // 0..3
  const int chunk = blockIdx.x;
  const int r0 = chunk * kT;
  const int rw0 = r0 + wv * 16;            // this wave's first row

  float wr[4][4][5];
#pragma unroll
  for (int j = 0; j < 4; ++j)
#pragma unroll
    for (int k = 0; k < 4; ++k) {
      const int d = j * 256 + lane * 4 + k;
#pragma unroll
      for (int f = 0; f < 5; ++f) wr[j][k][f] = Wl[d * 5 + f];
    }

  // Resolve noise + threshold for this wave's 16 rows up front.
  float nu = 0.5f, nth = 0.0f;
  if (lane < 16) {
    nu = noise[rw0 + lane];
    nth = logf(nu / (1.0f - nu));  // u==0 -> -inf -> always sample 1
  }

  auto pref = [&](float4(&v)[4], int t) {
    if (t < 16) {
      const float4* xp =
          reinterpret_cast<const float4*>(x + (size_t)(rw0 + t) * kD);
#pragma unroll
      for (int j = 0; j < 4; ++j) v[j] = xp[j * 64 + lane];
    }
  };

  auto do_row = [&](const float4(&v)[4], int t) {
    float acc[5] = {0.f, 0.f, 0.f, 0.f, 0.f};
#pragma unroll
    for (int j = 0; j < 4; ++j) {
      const float e[4] = {v[j].x, v[j].y, v[j].z, v[j].w};
#pragma unroll
      for (int k = 0; k < 4; ++k)
#pragma unroll
        for (int f = 0; f < 5; ++f) acc[f] += e[k] * wr[j][k][f];
    }
#pragma unroll
    for (int off = 32; off >= 1; off >>= 1)
#pragma unroll
      for (int f = 0; f < 5; ++f) acc[f] += __shfl_xor(acc[f], off);

    const float u = __shfl(nu, t);
    const float th = __shfl(nth, t);
    if (lane == 0) {
      const int row = rw0 + t;
      const float4 o0 = make_float4(acc[0], acc[1], acc[2], acc[3]);
      const float4 o1 = make_float4(acc[4], u, th, 0.0f);
      float4* og = reinterpret_cast<float4*>(fwu + (size_t)row * 8);
      og[0] = o0;
      og[1] = o1;
      float4* ol = reinterpret_cast<float4*>(&fl[(wv * 16 + t) * 8]);
      ol[0] = o0;
      ol[1] = o1;
    }
  };

  // Depth-2 software pipeline over the wave's 16 rows.
  float4 va[4], vb[4];
  pref(va, 0);
  pref(vb, 1);
#pragma unroll 1
  for (int tp = 0; tp < 8; ++tp) {
    do_row(va, 2 * tp);
    pref(va, 2 * tp + 2);
    do_row(vb, 2 * tp + 1);
    pref(vb, 2 * tp + 3);
  }
  __syncthreads();

  // Wave 0: speculative 16-state simulation of the 64 steps from LDS.
  if (wv == 0) {
    unsigned int cur = (unsigned int)(lane & 15);
    unsigned long long traj = 0;
#pragma unroll 8
    for (int i = 0; i < kT; ++i) {
      const float4* p = reinterpret_cast<const float4*>(&fl[i * 8]);
      const float4 A = p[0];
      const float4 Bv = p[1];  // Bv.x=fw4, Bv.y=u, Bv.z=th
      const unsigned int d = (logit_from_state(cur, A, Bv) > Bv.z) ? 1u : 0u;
      traj |= (unsigned long long)d << i;
      cur = (cur >> 1) | (d << 3);
    }
    if (lane < 16) trajbuf[(size_t)chunk * 16 + lane] = traj;
    const unsigned long long b0 = __ballot((int)(cur & 1u));
    const unsigned long long b1 = __ballot((int)(cur & 2u));
    const unsigned long long b2 = __ballot((int)(cur & 4u));
    const unsigned long long b3 = __ballot((int)(cur & 8u));
    if (lane == 0) {
      unsigned long long m = 0;
#pragma unroll
      for (int s = 0; s < 16; ++s) {
        const unsigned long long e =
            ((b0 >> s) & 1ull) | (((b1 >> s) & 1ull) << 1) |
            (((b2 >> s) & 1ull) << 2) | (((b3 >> s) & 1ull) << 3);
        m |= e << (4 * s);
      }
      maps[chunk] = m;
    }
  }
}

// ---------------------------------------------------------------- K2
// Block = 4 chunks (within one batch since 4 | 128). fwu fragment and all 16
// candidate trajs are loaded before the scan barrier; traj picked via shfl.
__global__ __launch_bounds__(256) void scan_emit_kernel(
    const float* __restrict__ fwu, const unsigned long long* __restrict__ maps,
    const unsigned long long* __restrict__ trajbuf, float* __restrict__ out) {
  __shared__ unsigned int starts_lds[kCPB];
  const int tid = threadIdx.x;
  const int lane = tid & 63;
  const int wv = tid >> 6;
  const int c0 = blockIdx.x * 4;
  const int b = c0 / kCPB;
  const int chunk = c0 + wv;
  const int row = chunk * kT + lane;

  // Issue independent loads early (latency hides under the scan).
  const float4* p = reinterpret_cast<const float4*>(fwu + (size_t)row * 8);
  const float4 A = p[0];
  const float4 Bv = p[1];
  unsigned long long tj = 0;
  if (lane < 16) tj = trajbuf[(size_t)chunk * 16 + lane];

  if (wv == 0) {
    const int L = lane;
    const unsigned long long m0 = maps[b * kCPB + 2 * L];
    const unsigned long long m1 = maps[b * kCPB + 2 * L + 1];
    unsigned long long scan = compose(m0, m1);
#pragma unroll
    for (int off = 1; off < 64; off <<= 1) {
      const unsigned long long prev = __shfl_up(scan, off);
      if (L >= off) scan = compose(prev, scan);
    }
    unsigned long long pref = __shfl_up(scan, 1);
    if (L == 0) pref = kIdMap;
    const unsigned int s0 = (unsigned int)(pref & 15ull);  // state before 2L
    starts_lds[2 * L] = s0;
    starts_lds[2 * L + 1] = (unsigned int)((m0 >> (4 * s0)) & 15ull);
  }
  __syncthreads();

  const unsigned int st = starts_lds[chunk & (kCPB - 1)];
  const unsigned long long traj = __shfl(tj, (int)st);

  unsigned int w;
  if (lane >= 4)
    w = (unsigned int)(traj >> (lane - 4)) & 15u;
  else
    w = ((st >> lane) | ((unsigned int)traj << (4 - lane))) & 15u;

  const float logit = logit_from_state(w, A, Bv);  // identical recompute
  const float pr = 1.0f / (1.0f + expf(-logit));
  const float lp = fminf(logit, 0.0f) - log1pf(expf(-fabsf(logit)));
  out[row] = lp;                                        // gate_logits (= logp)
  out[kRows + row] = pr;                                // gate_probs
  out[2 * kRows + row] = (float)((traj >> lane) & 1ull);  // gate_samples
}

extern "C" void kernel_launch(void* const* d_in, const int* in_sizes, int n_in,
                              void* d_out, int out_size, void* d_ws,
                              size_t ws_size, hipStream_t stream) {
  const float* x = (const float*)d_in[0];
  const float* W = (const float*)d_in[1];
  const float* noise = (const float*)d_in[2];
  float* out = (float*)d_out;

  // ws layout: fwu (65536*8 f32 = 2 MB) | trajbuf (1024*16 u64 = 128 KB)
  //            | maps (1024 u64 = 8 KB)
  float* fwu = (float*)d_ws;
  unsigned long long* trajbuf =
      (unsigned long long*)((char*)d_ws + (size_t)kRows * 8 * sizeof(float));
  unsigned long long* maps =
      (unsigned long long*)((char*)trajbuf +
                            (size_t)kChunks * 16 * sizeof(unsigned long long));

  proj_map_kernel<<<kChunks, 256, 0, stream>>>(x, W, noise, fwu, trajbuf, maps);
  scan_emit_kernel<<<kChunks / 4, 256, 0, stream>>>(fwu, maps, trajbuf, out);
}

// Round 5
// 54.947 us; speedup vs baseline: 1.1075x; 1.1075x over previous
//
#include <hip/hip_runtime.h>
#include <cstdint>
#include <cstddef>

// SequentiallyDependentGater on MI355X — R5: fully wave-independent streaming.
//
//   K1 proj_map : wave = 32 rows = 2 independent 16-step sub-chunks.
//                 After the W-staging barrier there is NO cross-wave sync:
//                 each wave streams its rows (depth-2 float4 prefetch,
//                 butterfly reduce, W in 80 VGPRs), parks fw rows in a
//                 PRIVATE LDS slice, and sims its own 16-state/16-step
//                 sub-chunk inline (decision bitstrings traj u32 + 16-entry
//                 end-state map u64 via ballot bitplanes). No block tail.
//   K2 scan_emit: block = 256 rows. Wave 0 redundantly scans its batch's 512
//                 sub-chunk maps (lane owns 8: serial compose + Hillis-Steele
//                 + 8-step start walk) -> starts in LDS; fully parallel emit.
//
// Decision rule everywhere: samp = (logit > th), th = log(u/(1-u)) — monotone-
// equivalent to u < sigmoid(logit) incl. ties. K1's sim is the single point
// where decisions are made; K2 recomputes logit from identical fwu bits with
// the identical pure-add/select expression (bit-exact, no FMA contraction).

namespace {

constexpr int kB = 8;
constexpr int kS = 8192;
constexpr int kD = 1024;
constexpr int kRows = kB * kS;          // 65536
constexpr int kT = 16;                  // sub-chunk steps (per-wave sim unit)
constexpr int kCPB = kS / kT;           // 512 sub-chunks per batch
constexpr int kChunks = kB * kCPB;      // 4096
constexpr int kRPW = 32;                // rows per wave in K1 (2 sub-chunks)
constexpr unsigned long long kIdMap = 0xFEDCBA9876543210ull;

// window bit i = window[i] (oldest first). logit = fw0 + sum(bit_i * fw[i+1]).
// fwu row layout: [fw0, fw1, fw2, fw3] [fw4, u, th, pad]
__device__ __forceinline__ float logit_from_state(unsigned int w,
                                                  const float4& A,
                                                  const float4& Bv) {
  const float s1 = (w & 1u) ? A.y : 0.0f;
  const float s2 = (w & 2u) ? A.z : 0.0f;
  const float s3 = (w & 4u) ? A.w : 0.0f;
  const float s4 = (w & 8u) ? Bv.x : 0.0f;
  return A.x + (((s1 + s2) + s3) + s4);
}

// 16-entry 4-bit maps packed in u64; result[s] = b[a[s]] ("a then b").
__device__ __forceinline__ unsigned long long compose(unsigned long long a,
                                                      unsigned long long b) {
  unsigned long long r = 0;
#pragma unroll
  for (int s = 0; s < 16; ++s) {
    const unsigned int e = (unsigned int)(a >> (4 * s)) & 15u;
    r |= ((b >> (4 * e)) & 15ull) << (4 * s);
  }
  return r;
}

}  // namespace

// ---------------------------------------------------------------- K1
__global__ __launch_bounds__(256, 2) void proj_map_kernel(
    const float* __restrict__ x, const float* __restrict__ W,
    const float* __restrict__ noise, float* __restrict__ fwu,
    unsigned int* __restrict__ trajbuf, unsigned long long* __restrict__ maps) {
  __shared__ float Wl[kD * 5];       // 20 KB
  __shared__ float fl[4][kT * 8];    // 2 KB, PER-WAVE private slices
  const int tid = threadIdx.x;
  const int lane = tid & 63;
  const int wv = tid >> 6;                   // 0..3
  const int wid = blockIdx.x * 4 + wv;       // 0..2047
  const int r0 = wid * kRPW;                 // wave's first row

  // Noise for this wave's 32 rows: issue load before the W barrier.
  float nu = 0.5f, nth = 0.0f;
  if (lane < kRPW) nu = noise[r0 + lane];

  // Stage W coalesced into LDS, then into per-lane registers.
  const float4* W4 = reinterpret_cast<const float4*>(W);
  float4* Wl4 = reinterpret_cast<float4*>(Wl);
#pragma unroll
  for (int i = 0; i < 5; ++i) Wl4[tid + 256 * i] = W4[tid + 256 * i];

  if (lane < kRPW) nth = logf(nu / (1.0f - nu));  // u==0 -> -inf -> samp 1
  __syncthreads();   // the ONLY cross-wave sync

  float wr[4][4][5];
#pragma unroll
  for (int j = 0; j < 4; ++j)
#pragma unroll
    for (int k = 0; k < 4; ++k) {
      const int d = j * 256 + lane * 4 + k;
#pragma unroll
      for (int f = 0; f < 5; ++f) wr[j][k][f] = Wl[d * 5 + f];
    }

  auto prefetch_row = [&](float4(&v)[4], int t) {
    if (t < kRPW) {
      const float4* xp =
          reinterpret_cast<const float4*>(x + (size_t)(r0 + t) * kD);
#pragma unroll
      for (int j = 0; j < 4; ++j) v[j] = xp[j * 64 + lane];
    }
  };

  auto do_row = [&](const float4(&v)[4], int t) {
    float acc[5] = {0.f, 0.f, 0.f, 0.f, 0.f};
#pragma unroll
    for (int j = 0; j < 4; ++j) {
      const float e[4] = {v[j].x, v[j].y, v[j].z, v[j].w};
#pragma unroll
      for (int k = 0; k < 4; ++k)
#pragma unroll
        for (int f = 0; f < 5; ++f) acc[f] += e[k] * wr[j][k][f];
    }
#pragma unroll
    for (int off = 32; off >= 1; off >>= 1)
#pragma unroll
      for (int f = 0; f < 5; ++f) acc[f] += __shfl_xor(acc[f], off);

    const float u = __shfl(nu, t);
    const float th = __shfl(nth, t);
    if (lane == 0) {
      const float4 o0 = make_float4(acc[0], acc[1], acc[2], acc[3]);
      const float4 o1 = make_float4(acc[4], u, th, 0.0f);
      float4* og = reinterpret_cast<float4*>(fwu + (size_t)(r0 + t) * 8);
      og[0] = o0;
      og[1] = o1;
      float4* ol = reinterpret_cast<float4*>(&fl[wv][(t & 15) * 8]);
      ol[0] = o0;
      ol[1] = o1;
    }
  };

  // 16-state / 16-step speculative sim of sub-chunk c from the wave's private
  // LDS slice. Same-wave LDS write->read: in-order, no barrier needed.
  auto sim = [&](int c) {
    unsigned int cur = (unsigned int)(lane & 15);
    unsigned int traj = 0;
#pragma unroll
    for (int i = 0; i < kT; ++i) {
      const float4* p = reinterpret_cast<const float4*>(&fl[wv][i * 8]);
      const float4 A = p[0];
      const float4 Bv = p[1];  // Bv.x=fw4, Bv.y=u, Bv.z=th
      const unsigned int d = (logit_from_state(cur, A, Bv) > Bv.z) ? 1u : 0u;
      traj |= d << i;
      cur = (cur >> 1) | (d << 3);
    }
    if (lane < 16) trajbuf[(size_t)c * 16 + lane] = traj;
    // lanes >=16 mirror lane&15 (identical deterministic inputs) -> low 16
    // bits of each ballot plane are the 16-entry map bitplanes.
    const unsigned long long b0 = __ballot((int)(cur & 1u));
    const unsigned long long b1 = __ballot((int)(cur & 2u));
    const unsigned long long b2 = __ballot((int)(cur & 4u));
    const unsigned long long b3 = __ballot((int)(cur & 8u));
    if (lane == 0) {
      unsigned long long m = 0;
#pragma unroll
      for (int s = 0; s < 16; ++s) {
        const unsigned long long e =
            ((b0 >> s) & 1ull) | (((b1 >> s) & 1ull) << 1) |
            (((b2 >> s) & 1ull) << 2) | (((b3 >> s) & 1ull) << 3);
        m |= e << (4 * s);
      }
      maps[c] = m;
    }
  };

  // Depth-2 software pipeline over the wave's 32 rows; sims run inline after
  // each 16-row group, overlapped with the next group's in-flight loads.
  float4 va[4], vb[4];
  prefetch_row(va, 0);
  prefetch_row(vb, 1);
#pragma unroll 1
  for (int tp = 0; tp < 16; ++tp) {
    do_row(va, 2 * tp);
    prefetch_row(va, 2 * tp + 2);
    do_row(vb, 2 * tp + 1);
    prefetch_row(vb, 2 * tp + 3);
    if (tp == 7) sim(wid * 2);
    if (tp == 15) sim(wid * 2 + 1);
  }
}

// ---------------------------------------------------------------- K2
// Block = 256 rows (16 sub-chunks), 32 blocks per batch. Wave 0 redundantly
// scans the batch's 512 maps; emit is fully parallel.
__global__ __launch_bounds__(256) void scan_emit_kernel(
    const float* __restrict__ fwu, const unsigned long long* __restrict__ maps,
    const unsigned int* __restrict__ trajbuf, float* __restrict__ out) {
  __shared__ unsigned char starts_lds[kCPB];   // 512 B
  const int tid = threadIdx.x;
  const int lane = tid & 63;
  const int wv = tid >> 6;
  const int bid = blockIdx.x;
  const int b = bid >> 5;                      // batch (32 blocks/batch)
  const int row = bid * 256 + tid;

  // Issue independent loads early (latency hides under the scan).
  const float4* p = reinterpret_cast<const float4*>(fwu + (size_t)row * 8);
  const float4 A = p[0];
  const float4 Bv = p[1];

  if (wv == 0) {
    unsigned long long m[8];
    const unsigned long long* mb = maps + b * kCPB + lane * 8;
#pragma unroll
    for (int i = 0; i < 8; ++i) m[i] = mb[i];
    unsigned long long c = m[0];
#pragma unroll
    for (int i = 1; i < 8; ++i) c = compose(c, m[i]);
    unsigned long long scan = c;
#pragma unroll
    for (int off = 1; off < 64; off <<= 1) {
      const unsigned long long prev = __shfl_up(scan, off);
      if (lane >= off) scan = compose(prev, scan);
    }
    unsigned long long pref = __shfl_up(scan, 1);
    if (lane == 0) pref = kIdMap;
    unsigned int s = (unsigned int)(pref & 15ull);  // state entering chunk 8L
#pragma unroll
    for (int i = 0; i < 8; ++i) {
      starts_lds[lane * 8 + i] = (unsigned char)s;
      s = (unsigned int)((m[i] >> (4 * s)) & 15ull);
    }
  }
  __syncthreads();

  const int scl = (row & (kS - 1)) >> 4;   // batch-local sub-chunk 0..511
  const int scg = row >> 4;                // global sub-chunk
  const unsigned int st = (unsigned int)starts_lds[scl];
  const unsigned int traj = trajbuf[(size_t)scg * 16 + st];
  const int i = row & 15;
  unsigned int w;
  if (i >= 4)
    w = (traj >> (i - 4)) & 15u;
  else
    w = ((st >> i) | (traj << (4 - i))) & 15u;

  const float logit = logit_from_state(w, A, Bv);  // identical recompute
  const float pr = 1.0f / (1.0f + expf(-logit));
  const float lp = fminf(logit, 0.0f) - log1pf(expf(-fabsf(logit)));
  out[row] = lp;                                      // gate_logits (= logp)
  out[kRows + row] = pr;                              // gate_probs
  out[2 * kRows + row] = (float)((traj >> i) & 1u);   // gate_samples
}

extern "C" void kernel_launch(void* const* d_in, const int* in_sizes, int n_in,
                              void* d_out, int out_size, void* d_ws,
                              size_t ws_size, hipStream_t stream) {
  const float* x = (const float*)d_in[0];
  const float* W = (const float*)d_in[1];
  const float* noise = (const float*)d_in[2];
  float* out = (float*)d_out;

  // ws layout: fwu (65536*8 f32 = 2 MB) | trajbuf (4096*16 u32 = 256 KB)
  //            | maps (4096 u64 = 32 KB)
  float* fwu = (float*)d_ws;
  unsigned int* trajbuf =
      (unsigned int*)((char*)d_ws + (size_t)kRows * 8 * sizeof(float));
  unsigned long long* maps =
      (unsigned long long*)((char*)trajbuf +
                            (size_t)kChunks * 16 * sizeof(unsigned int));

  proj_map_kernel<<<512, 256, 0, stream>>>(x, W, noise, fwu, trajbuf, maps);
  scan_emit_kernel<<<kRows / 256, 256, 0, stream>>>(fwu, maps, trajbuf, out);
}